// Round 10
// baseline (530.282 us; speedup 1.0000x reference)
//
#include <hip/hip_runtime.h>
#include <math.h>

// RiskGAT: 2-layer GAT (PyG GATConv, concat=True, self-loops) + linear + sigmoid.
// N=100000, E=1600000. L1: in=4,H=4,D=16 (F=64). L2: in=64,H=2,D=8 (F=16).
//
// R9 -> R10: CSR build eliminated (kb_build + csr were ~40% of runtime; R9 showed agg
// loops latency-bound, so per-node iteration isn't needed). New structure: edges are
// bucket-contiguous in ebuf (256 nodes/bucket); ONE BLOCK PER BUCKET streams its edges
// coalesced and accumulates (p*x | p*h2, den) into LDS FLOAT ATOMICS (ds_add_f32)
// indexed by dlocal. Self-loops folded into the per-node epilogue (R7 linearity + sE
// transpose kept). LDS strides 5/19/65 (gcd with 32 = 1) for bank spread.
// Pipeline: memset, kb_scatter, kA1, kA2 (4 dispatches).

#define NEG_SLOPE 0.2f
#define SHIFT 8                 // 256 nodes per bucket
#define BN 256
#define BMASK 255
#define CAPB 8192               // per-bucket region capacity (mean ~4092, >60-sigma)

__device__ __forceinline__ float lrelu(float v) { return v >= 0.f ? v : NEG_SLOPE * v; }

// ---------------- Pass A: scatter packed (dlocal<<17 | src) into bucket regions ----------
__global__ void kb_scatter(const int* __restrict__ src, const int* __restrict__ dst,
                           int* __restrict__ bcur, unsigned* __restrict__ ebuf, int E) {
    __shared__ int lh[512], lbase[512], loff[512];
    int t = threadIdx.x;
    lh[t] = 0; lh[t + 256] = 0;
    __syncthreads();
    const int4* src4 = reinterpret_cast<const int4*>(src);
    const int4* dst4 = reinterpret_cast<const int4*>(dst);
    int base4 = blockIdx.x * 1024;           // 4096 edges = 1024 int4
    int myb[16];
    unsigned myv[16];
#pragma unroll
    for (int it = 0; it < 4; ++it) {
        int i4 = base4 + it * 256 + t;
        if (i4 * 4 < E) {                    // E % 4 == 0
            int4 s4 = src4[i4], d4 = dst4[i4];
            int ss[4] = {s4.x, s4.y, s4.z, s4.w};
            int dd[4] = {d4.x, d4.y, d4.z, d4.w};
#pragma unroll
            for (int c = 0; c < 4; ++c) {
                int b = dd[c] >> SHIFT;
                myb[it * 4 + c] = b;
                myv[it * 4 + c] = (unsigned)ss[c] | ((unsigned)(dd[c] & BMASK) << 17);
                atomicAdd(&lh[b], 1);
            }
        } else {
#pragma unroll
            for (int c = 0; c < 4; ++c) myb[it * 4 + c] = -1;
        }
    }
    __syncthreads();
    if (lh[t]) lbase[t] = atomicAdd(&bcur[t], lh[t]);
    if (lh[t + 256]) lbase[t + 256] = atomicAdd(&bcur[t + 256], lh[t + 256]);
    loff[t] = 0; loff[t + 256] = 0;
    __syncthreads();
#pragma unroll
    for (int it = 0; it < 16; ++it) {
        int b = myb[it];
        if (b >= 0) {
            int o = lbase[b] + atomicAdd(&loff[b], 1);
            if (o < CAPB) ebuf[(size_t)b * CAPB + o] = myv[it];
        }
    }
}

// ---------------- kA1: bucket-resident L1 agg (LDS atomics) + epilogue + L2 node phase ----
// accD layout [h][dl][5] (acc0..3,den): addr = h*BN*5 + dl*5 + c  -> stride 5, full banks.
__global__ void __launch_bounds__(512) kA1(
        const float* __restrict__ x, const float* __restrict__ W1,
        const float* __restrict__ as1, const float* __restrict__ ad1,
        const float* __restrict__ b1, const float* __restrict__ W2,
        const float* __restrict__ as2, const float* __restrict__ ad2,
        const int* __restrict__ bcur, const unsigned* __restrict__ ebuf,
        float* __restrict__ h2, float* __restrict__ als2, float* __restrict__ ald2, int N)
{
    __shared__ float sW[256], swals[16], swald[16], sb1[64], sW2[1024], sas2[16], sad2[16];
    __shared__ float aldL[BN * 5];       // [dl][4 heads] stride 5
    __shared__ float accD[4 * BN * 5];   // [h][dl][acc0..3,den]
    __shared__ float sE[128 * 65];       // 128 nodes/iter x 64 e0, stride 65
    int t = threadIdx.x, b = blockIdx.x;
    if (t < 256) sW[t] = W1[t];
    for (int i = t; i < 1024; i += 512) sW2[i] = W2[i];
    if (t < 64) sb1[t] = b1[t];
    if (t >= 64 && t < 80) { sas2[t - 64] = as2[t - 64]; sad2[t - 64] = ad2[t - 64]; }
    __syncthreads();
    if (t < 16) {
        int head = t >> 2, i = t & 3;
        float s1 = 0.f, s2 = 0.f;
        for (int d = 0; d < 16; ++d) {
            float w = sW[i * 64 + head * 16 + d];
            s1 += w * as1[head * 16 + d];
            s2 += w * ad1[head * 16 + d];
        }
        swals[t] = s1;    // (W1_h @ a_src_h)[i]
        swald[t] = s2;
    }
    for (int i = t; i < 4 * BN * 5; i += 512) accD[i] = 0.f;
    __syncthreads();

    int node0 = b << SHIFT;
    int nn = min(BN, N - node0);
    const float4* x4 = reinterpret_cast<const float4*>(x);
    for (int j = t; j < nn; j += 512) {
        float4 xd = x4[node0 + j];
#pragma unroll
        for (int h = 0; h < 4; ++h)
            aldL[j * 5 + h] = xd.x * swald[h * 4 + 0] + xd.y * swald[h * 4 + 1]
                            + xd.z * swald[h * 4 + 2] + xd.w * swald[h * 4 + 3];
    }
    __syncthreads();

    float wa[16];
#pragma unroll
    for (int i = 0; i < 16; ++i) wa[i] = swals[i];

    int ne = min(bcur[b], CAPB);
    const unsigned* eb = ebuf + (size_t)b * CAPB;
    for (int i = t; i < ne; i += 512) {
        unsigned pk = eb[i];
        int s = pk & 0x1FFFF, dl = pk >> 17;
        float4 xs = x4[s];
#pragma unroll
        for (int h = 0; h < 4; ++h) {
            float v = lrelu(fmaf(xs.x, wa[h * 4 + 0], fmaf(xs.y, wa[h * 4 + 1],
                       fmaf(xs.z, wa[h * 4 + 2], fmaf(xs.w, wa[h * 4 + 3], aldL[dl * 5 + h])))));
            float p = __expf(v);
            float* ap = &accD[(h * BN + dl) * 5];
            atomicAdd(ap + 0, p * xs.x);
            atomicAdd(ap + 1, p * xs.y);
            atomicAdd(ap + 2, p * xs.z);
            atomicAdd(ap + 3, p * xs.w);
            atomicAdd(ap + 4, p);
        }
    }
    __syncthreads();

    // ---- epilogue: 2 iters x 128 nodes, 4 lanes/node (lane = head) ----
    int g = t >> 2, tt = t & 3;
#pragma unroll
    for (int iter = 0; iter < 2; ++iter) {
        int j = iter * 128 + g;
        int n = node0 + j;
        bool act = j < nn;
        float a0 = 0.f, a1 = 0.f, a2 = 0.f, a3 = 0.f;
        float4 xn = make_float4(0.f, 0.f, 0.f, 0.f);
        if (act) {
            xn = x4[n];
            const float* ap = &accD[(tt * BN + j) * 5];
            a0 = ap[0]; a1 = ap[1]; a2 = ap[2]; a3 = ap[3];
            float den = ap[4];
            float als_s = xn.x * wa[tt * 4 + 0] + xn.y * wa[tt * 4 + 1]
                        + xn.z * wa[tt * 4 + 2] + xn.w * wa[tt * 4 + 3];
            float ps = __expf(lrelu(als_s + aldL[j * 5 + tt]));   // self loop
            den += ps;
            a0 = fmaf(ps, xn.x, a0); a1 = fmaf(ps, xn.y, a1);
            a2 = fmaf(ps, xn.z, a2); a3 = fmaf(ps, xn.w, a3);
            float inv = 1.f / (den + 1e-16f);
            a0 *= inv; a1 *= inv; a2 *= inv; a3 *= inv;
        }
#pragma unroll
        for (int d = 0; d < 16; ++d) {
            int col = tt * 16 + d;
            float v = a0 * sW[col] + a1 * sW[64 + col] + a2 * sW[128 + col]
                    + a3 * sW[192 + col] + sb1[col];
            sE[g * 65 + col] = v > 0.f ? v : expm1f(v);
        }
        // 4 lanes of a group are in the same wave: no barrier needed for sE row
        float o0 = 0.f, o1 = 0.f, o2 = 0.f, o3 = 0.f;
#pragma unroll
        for (int k = 0; k < 64; ++k) {
            float ev = sE[g * 65 + k];
            o0 = fmaf(ev, sW2[k * 16 + tt * 4 + 0], o0);
            o1 = fmaf(ev, sW2[k * 16 + tt * 4 + 1], o1);
            o2 = fmaf(ev, sW2[k * 16 + tt * 4 + 2], o2);
            o3 = fmaf(ev, sW2[k * 16 + tt * 4 + 3], o3);
        }
        if (act)
            reinterpret_cast<float4*>(h2)[(size_t)n * 4 + tt] = make_float4(o0, o1, o2, o3);
        int head2 = tt >> 1, half = tt & 1;
        const float* s2p = sas2 + head2 * 8 + half * 4;
        const float* d2p = sad2 + head2 * 8 + half * 4;
        float qs = o0 * s2p[0] + o1 * s2p[1] + o2 * s2p[2] + o3 * s2p[3];
        float qd = o0 * d2p[0] + o1 * d2p[1] + o2 * d2p[2] + o3 * d2p[3];
        qs += __shfl_xor(qs, 1);
        qd += __shfl_xor(qd, 1);
        if (act && half == 0) {
            als2[n * 2 + head2] = qs;
            ald2[n * 2 + head2] = qd;
        }
    }
}

// ---------------- kA2: bucket-resident L2 agg (LDS atomics) + linear head + sigmoid ------
// accD2 layout [dl][19]: dims 0..15 (head = dim>>3), den0 @16, den1 @17 (pad to 19).
__global__ void __launch_bounds__(512) kA2(
        const float* __restrict__ h2, const float* __restrict__ als2,
        const float* __restrict__ ald2, const float* __restrict__ b2,
        const float* __restrict__ lw, const float* __restrict__ lb,
        const int* __restrict__ bcur, const unsigned* __restrict__ ebuf,
        float* __restrict__ out, int N)
{
    __shared__ float ald2L[BN * 2];
    __shared__ float accD2[BN * 19];
    int t = threadIdx.x, b = blockIdx.x;
    int node0 = b << SHIFT;
    int nn = min(BN, N - node0);
    for (int j = t; j < nn * 2; j += 512) ald2L[j] = ald2[node0 * 2 + j];
    for (int i = t; i < BN * 19; i += 512) accD2[i] = 0.f;
    __syncthreads();

    const float4* h4 = reinterpret_cast<const float4*>(h2);
    const float2* als22 = reinterpret_cast<const float2*>(als2);
    int ne = min(bcur[b], CAPB);
    const unsigned* eb = ebuf + (size_t)b * CAPB;
    for (int i = t; i < ne; i += 512) {
        unsigned pk = eb[i];
        int s = pk & 0x1FFFF, dl = pk >> 17;
        float2 av = als22[s];
        float v0 = lrelu(av.x + ald2L[dl * 2 + 0]);
        float v1 = lrelu(av.y + ald2L[dl * 2 + 1]);
        float p0 = __expf(v0), p1 = __expf(v1);
        float4 hA = h4[(size_t)s * 4 + 0], hB = h4[(size_t)s * 4 + 1];
        float4 hC = h4[(size_t)s * 4 + 2], hD = h4[(size_t)s * 4 + 3];
        float* ap = &accD2[dl * 19];
        atomicAdd(ap + 0,  p0 * hA.x); atomicAdd(ap + 1,  p0 * hA.y);
        atomicAdd(ap + 2,  p0 * hA.z); atomicAdd(ap + 3,  p0 * hA.w);
        atomicAdd(ap + 4,  p0 * hB.x); atomicAdd(ap + 5,  p0 * hB.y);
        atomicAdd(ap + 6,  p0 * hB.z); atomicAdd(ap + 7,  p0 * hB.w);
        atomicAdd(ap + 8,  p1 * hC.x); atomicAdd(ap + 9,  p1 * hC.y);
        atomicAdd(ap + 10, p1 * hC.z); atomicAdd(ap + 11, p1 * hC.w);
        atomicAdd(ap + 12, p1 * hD.x); atomicAdd(ap + 13, p1 * hD.y);
        atomicAdd(ap + 14, p1 * hD.z); atomicAdd(ap + 15, p1 * hD.w);
        atomicAdd(ap + 16, p0);        atomicAdd(ap + 17, p1);
    }
    __syncthreads();

    // ---- epilogue: 1 thread per node ----
    if (t < BN && t < nn) {
        int j = t, n = node0 + j;
        const float* ap = &accD2[j * 19];
        float2 av = als22[n];
        float ps0 = __expf(lrelu(av.x + ald2L[j * 2 + 0]));
        float ps1 = __expf(lrelu(av.y + ald2L[j * 2 + 1]));
        float4 hA = h4[(size_t)n * 4 + 0], hB = h4[(size_t)n * 4 + 1];
        float4 hC = h4[(size_t)n * 4 + 2], hD = h4[(size_t)n * 4 + 3];
        float hv[16] = {hA.x, hA.y, hA.z, hA.w, hB.x, hB.y, hB.z, hB.w,
                        hC.x, hC.y, hC.z, hC.w, hD.x, hD.y, hD.z, hD.w};
        float inv0 = 1.f / (ap[16] + ps0 + 1e-16f);
        float inv1 = 1.f / (ap[17] + ps1 + 1e-16f);
        float dot = 0.f;
#pragma unroll
        for (int c = 0; c < 16; ++c) {
            float p = (c < 8) ? ps0 : ps1;
            float inv = (c < 8) ? inv0 : inv1;
            float v = (ap[c] + p * hv[c]) * inv + b2[c];
            v = v > 0.f ? v : expm1f(v);
            dot += v * lw[c];
        }
        out[n] = 1.f / (1.f + __expf(-(dot + lb[0])));
    }
}

extern "C" void kernel_launch(void* const* d_in, const int* in_sizes, int n_in,
                              void* d_out, int out_size, void* d_ws, size_t ws_size,
                              hipStream_t stream) {
    const float* x     = (const float*)d_in[0];
    const int*   eidx  = (const int*)d_in[1];
    const float* W1    = (const float*)d_in[2];
    const float* as1   = (const float*)d_in[3];
    const float* ad1   = (const float*)d_in[4];
    const float* b1    = (const float*)d_in[5];
    const float* W2    = (const float*)d_in[6];
    const float* as2   = (const float*)d_in[7];
    const float* ad2   = (const float*)d_in[8];
    const float* b2    = (const float*)d_in[9];
    const float* lin_w = (const float*)d_in[10];
    const float* lin_b = (const float*)d_in[11];
    float* out = (float*)d_out;

    const int N = in_sizes[0] / 4;
    const int E = in_sizes[1] / 2;
    const int* src = eidx;
    const int* dst = eidx + E;
    const int NB = (N + BMASK) >> SHIFT;   // 391 buckets of 256 nodes

    // ---- workspace layout ----
    int*      bcur = (int*)d_ws;                         // 512
    unsigned* ebuf = (unsigned*)(bcur + 512);            // NB*CAPB
    float*    h2   = (float*)(ebuf + (size_t)NB * CAPB); // N*16
    float*    als2 = h2 + (size_t)N * 16;                // N*2
    float*    ald2 = als2 + (size_t)N * 2;               // N*2

    hipMemsetAsync(bcur, 0, 512 * sizeof(int), stream);
    kb_scatter<<<(E + 4095) / 4096, 256, 0, stream>>>(src, dst, bcur, ebuf, E);
    kA1<<<NB, 512, 0, stream>>>(x, W1, as1, ad1, b1, W2, as2, ad2,
                                bcur, ebuf, h2, als2, ald2, N);
    kA2<<<NB, 512, 0, stream>>>(h2, als2, ald2, b2, lin_w, lin_b,
                                bcur, ebuf, out, N);
}

// Round 11
// 164.466 us; speedup vs baseline: 3.2243x; 3.2243x over previous
//
#include <hip/hip_runtime.h>
#include <math.h>

// RiskGAT: 2-layer GAT (PyG GATConv, concat=True, self-loops) + linear + sigmoid.
// N=100000, E=1600000. L1: in=4,H=4,D=16 (F=64). L2: in=64,H=2,D=8 (F=16).
//
// R10 -> R11: R10's per-edge LDS float atomics (20/edge) serialized the DS pipe
// (kA1 236us, VALUBusy 4.4%) -- REVERTED. This round keeps R9's validated pieces
// (counting sort: 2 LDS ops/edge; per-node register agg: dual-stream, 4 lanes/node)
// but FUSES sort+agg per bucket so the edge list lives in LDS `stage` and the csr
// global round-trip (12.8MB w+r), kb_build launch, and rstart/cnt globals disappear.
// Layer 2 re-sorts from ebuf instead of reading a materialized csr.

#define NEG_SLOPE 0.2f
#define SHIFT 8                 // 256 nodes per bucket
#define BN 256
#define BMASK 255
#define CAPB 8192               // per-bucket region capacity (mean ~4092, >60-sigma)
#define STCAP 6144              // LDS stage capacity (mean ~4092, >30-sigma)

__device__ __forceinline__ float lrelu(float v) { return v >= 0.f ? v : NEG_SLOPE * v; }

// ---------------- Pass A: scatter packed (dlocal<<17 | src) into bucket regions ----------
__global__ void kb_scatter(const int* __restrict__ src, const int* __restrict__ dst,
                           int* __restrict__ bcur, unsigned* __restrict__ ebuf, int E) {
    __shared__ int lh[512], lbase[512], loff[512];
    int t = threadIdx.x;
    lh[t] = 0; lh[t + 256] = 0;
    __syncthreads();
    const int4* src4 = reinterpret_cast<const int4*>(src);
    const int4* dst4 = reinterpret_cast<const int4*>(dst);
    int base4 = blockIdx.x * 1024;           // 4096 edges = 1024 int4
    int myb[16];
    unsigned myv[16];
#pragma unroll
    for (int it = 0; it < 4; ++it) {
        int i4 = base4 + it * 256 + t;
        if (i4 * 4 < E) {                    // E % 4 == 0
            int4 s4 = src4[i4], d4 = dst4[i4];
            int ss[4] = {s4.x, s4.y, s4.z, s4.w};
            int dd[4] = {d4.x, d4.y, d4.z, d4.w};
#pragma unroll
            for (int c = 0; c < 4; ++c) {
                int b = dd[c] >> SHIFT;
                myb[it * 4 + c] = b;
                myv[it * 4 + c] = (unsigned)ss[c] | ((unsigned)(dd[c] & BMASK) << 17);
                atomicAdd(&lh[b], 1);
            }
        } else {
#pragma unroll
            for (int c = 0; c < 4; ++c) myb[it * 4 + c] = -1;
        }
    }
    __syncthreads();
    if (lh[t]) lbase[t] = atomicAdd(&bcur[t], lh[t]);
    if (lh[t + 256]) lbase[t + 256] = atomicAdd(&bcur[t + 256], lh[t + 256]);
    loff[t] = 0; loff[t + 256] = 0;
    __syncthreads();
#pragma unroll
    for (int it = 0; it < 16; ++it) {
        int b = myb[it];
        if (b >= 0) {
            int o = lbase[b] + atomicAdd(&loff[b], 1);
            if (o < CAPB) ebuf[(size_t)b * CAPB + o] = myv[it];
        }
    }
}

// ---------------- kbA1: per-bucket LDS sort + L1 agg + epilogue + L2 node phase -----------
__global__ void __launch_bounds__(512) kbA1(
        const float* __restrict__ x, const float* __restrict__ W1,
        const float* __restrict__ as1, const float* __restrict__ ad1,
        const float* __restrict__ b1, const float* __restrict__ W2,
        const float* __restrict__ as2, const float* __restrict__ ad2,
        const int* __restrict__ bcur, const unsigned* __restrict__ ebuf,
        float* __restrict__ h2, float* __restrict__ als2, float* __restrict__ ald2, int N)
{
    __shared__ float sW[256], swals[16], swald[16], sb1[64], sW2[1024], sas2[16], sad2[16];
    __shared__ float aldL[BN * 5];       // [dl][head] stride 5
    __shared__ int nh[BN], ns[BN], stmp[BN];
    __shared__ int stage[STCAP];
    __shared__ float sE[128 * 65];       // 128 nodes/chunk x 64 e0, stride 65
    int t = threadIdx.x, b = blockIdx.x;
    if (t < 256) { sW[t] = W1[t]; nh[t] = 0; }
    for (int i = t; i < 1024; i += 512) sW2[i] = W2[i];
    if (t < 64) sb1[t] = b1[t];
    if (t >= 64 && t < 80) { sas2[t - 64] = as2[t - 64]; sad2[t - 64] = ad2[t - 64]; }
    __syncthreads();
    if (t < 16) {
        int head = t >> 2, i = t & 3;
        float s1 = 0.f, s2 = 0.f;
        for (int d = 0; d < 16; ++d) {
            float w = sW[i * 64 + head * 16 + d];
            s1 += w * as1[head * 16 + d];
            s2 += w * ad1[head * 16 + d];
        }
        swals[t] = s1;    // (W1_h @ a_src_h)[i]
        swald[t] = s2;
    }
    __syncthreads();

    int node0 = b << SHIFT;
    int nn = min(BN, N - node0);
    const float4* x4 = reinterpret_cast<const float4*>(x);
    int ne = min(bcur[b], STCAP);
    const unsigned* eb = ebuf + (size_t)b * CAPB;

    // hist + per-dst ald precompute
    for (int i = t; i < ne; i += 512) atomicAdd(&nh[eb[i] >> 17], 1);
    for (int j = t; j < nn; j += 512) {
        float4 xd = x4[node0 + j];
#pragma unroll
        for (int h = 0; h < 4; ++h)
            aldL[j * 5 + h] = xd.x * swald[h * 4 + 0] + xd.y * swald[h * 4 + 1]
                            + xd.z * swald[h * 4 + 2] + xd.w * swald[h * 4 + 3];
    }
    __syncthreads();

    // scan (exclusive) -> ns cursor
    int vcnt = 0;
    if (t < 256) { vcnt = nh[t]; stmp[t] = vcnt; }
    __syncthreads();
#pragma unroll
    for (int off = 1; off < 256; off <<= 1) {
        int a = 0;
        if (t < 256 && t >= off) a = stmp[t - off];
        __syncthreads();
        if (t < 256) stmp[t] += a;
        __syncthreads();
    }
    if (t < 256) ns[t] = stmp[t] - vcnt;
    __syncthreads();

    // counting-sort into LDS stage (src only; dl implied by segment)
    for (int i = t; i < ne; i += 512) {
        unsigned pk = eb[i];
        int pos = atomicAdd(&ns[pk >> 17], 1);
        stage[pos] = (int)(pk & 0x1FFFFu);
    }
    __syncthreads();

    // ---- agg: 4 lanes/node (lane = head), 2 chunks x 128 nodes ----
    int g = t >> 2, tt = t & 3;
    float wa0 = swals[tt * 4 + 0], wa1 = swals[tt * 4 + 1];
    float wa2 = swals[tt * 4 + 2], wa3 = swals[tt * 4 + 3];
#pragma unroll
    for (int c = 0; c < 2; ++c) {
        int j = c * 128 + g;
        int n = node0 + j;
        bool act = j < nn;
        int e = act ? nh[j] : 0;
        int st = act ? (ns[j] - e) : 0;     // cursor ended at start+cnt
        float aldv = act ? aldL[j * 5 + tt] : 0.f;
        float dA = 0.f, aA0 = 0.f, aA1 = 0.f, aA2 = 0.f, aA3 = 0.f;
        float dB = 0.f, aB0 = 0.f, aB1 = 0.f, aB2 = 0.f, aB3 = 0.f;
        int h = e >> 1;
        for (int i = 0; i < h; ++i) {
            int sA = stage[st + i];
            int sB = stage[st + h + i];
            float4 xA = x4[sA];
            float4 xB = x4[sB];
            float vA = lrelu(fmaf(xA.x, wa0, fmaf(xA.y, wa1, fmaf(xA.z, wa2, fmaf(xA.w, wa3, aldv)))));
            float vB = lrelu(fmaf(xB.x, wa0, fmaf(xB.y, wa1, fmaf(xB.z, wa2, fmaf(xB.w, wa3, aldv)))));
            float pA = __expf(vA);
            float pB = __expf(vB);
            dA += pA;                  dB += pB;
            aA0 = fmaf(pA, xA.x, aA0); aB0 = fmaf(pB, xB.x, aB0);
            aA1 = fmaf(pA, xA.y, aA1); aB1 = fmaf(pB, xB.y, aB1);
            aA2 = fmaf(pA, xA.z, aA2); aB2 = fmaf(pB, xB.z, aB2);
            aA3 = fmaf(pA, xA.w, aA3); aB3 = fmaf(pB, xB.w, aB3);
        }
        if (e & 1) {
            int s = stage[st + e - 1];
            float4 xs = x4[s];
            float v = lrelu(fmaf(xs.x, wa0, fmaf(xs.y, wa1, fmaf(xs.z, wa2, fmaf(xs.w, wa3, aldv)))));
            float p = __expf(v);
            dA += p;
            aA0 = fmaf(p, xs.x, aA0); aA1 = fmaf(p, xs.y, aA1);
            aA2 = fmaf(p, xs.z, aA2); aA3 = fmaf(p, xs.w, aA3);
        }
        // self loop + normalize
        float4 xn = act ? x4[n] : make_float4(0.f, 0.f, 0.f, 0.f);
        float als_s = xn.x * wa0 + xn.y * wa1 + xn.z * wa2 + xn.w * wa3;
        float ps = __expf(lrelu(als_s + aldv));
        float inv = 1.f / (dA + dB + ps + 1e-16f);
        float a0 = (aA0 + aB0 + ps * xn.x) * inv;
        float a1 = (aA1 + aB1 + ps * xn.y) * inv;
        float a2 = (aA2 + aB2 + ps * xn.z) * inv;
        float a3 = (aA3 + aB3 + ps * xn.w) * inv;

        // epilogue: e0 = elu((sum p*x)@W1_h + b1) -> sE row; own-column W2 dot
#pragma unroll
        for (int d = 0; d < 16; ++d) {
            int col = tt * 16 + d;
            float v = a0 * sW[col] + a1 * sW[64 + col] + a2 * sW[128 + col]
                    + a3 * sW[192 + col] + sb1[col];
            sE[g * 65 + col] = v > 0.f ? v : expm1f(v);
        }
        // 4 lanes of a group are in the same wave: row write->read is ordered
        float o0 = 0.f, o1 = 0.f, o2 = 0.f, o3 = 0.f;
#pragma unroll
        for (int k = 0; k < 64; ++k) {
            float ev = sE[g * 65 + k];
            o0 = fmaf(ev, sW2[k * 16 + tt * 4 + 0], o0);
            o1 = fmaf(ev, sW2[k * 16 + tt * 4 + 1], o1);
            o2 = fmaf(ev, sW2[k * 16 + tt * 4 + 2], o2);
            o3 = fmaf(ev, sW2[k * 16 + tt * 4 + 3], o3);
        }
        if (act)
            reinterpret_cast<float4*>(h2)[(size_t)n * 4 + tt] = make_float4(o0, o1, o2, o3);
        int head2 = tt >> 1, half = tt & 1;
        const float* s2p = sas2 + head2 * 8 + half * 4;
        const float* d2p = sad2 + head2 * 8 + half * 4;
        float qs = o0 * s2p[0] + o1 * s2p[1] + o2 * s2p[2] + o3 * s2p[3];
        float qd = o0 * d2p[0] + o1 * d2p[1] + o2 * d2p[2] + o3 * d2p[3];
        qs += __shfl_xor(qs, 1);
        qd += __shfl_xor(qd, 1);
        if (act && half == 0) {
            als2[n * 2 + head2] = qs;
            ald2[n * 2 + head2] = qd;
        }
    }
}

// ---------------- kbA2: per-bucket LDS sort + L2 agg + linear head + sigmoid --------------
__global__ void __launch_bounds__(512) kbA2(
        const float* __restrict__ h2, const float* __restrict__ als2,
        const float* __restrict__ ald2, const float* __restrict__ b2,
        const float* __restrict__ lw, const float* __restrict__ lb,
        const int* __restrict__ bcur, const unsigned* __restrict__ ebuf,
        float* __restrict__ out, int N)
{
    __shared__ int nh[BN], ns[BN], stmp[BN];
    __shared__ int stage[STCAP];
    __shared__ float ald2L[BN * 2];
    __shared__ float sb2[16], slw[16];
    int t = threadIdx.x, b = blockIdx.x;
    if (t < 256) nh[t] = 0;
    if (t < 16) { sb2[t] = b2[t]; slw[t] = lw[t]; }
    int node0 = b << SHIFT;
    int nn = min(BN, N - node0);
    __syncthreads();
    int ne = min(bcur[b], STCAP);
    const unsigned* eb = ebuf + (size_t)b * CAPB;
    for (int i = t; i < ne; i += 512) atomicAdd(&nh[eb[i] >> 17], 1);
    for (int j = t; j < nn * 2; j += 512) ald2L[j] = ald2[node0 * 2 + j];
    __syncthreads();
    int vcnt = 0;
    if (t < 256) { vcnt = nh[t]; stmp[t] = vcnt; }
    __syncthreads();
#pragma unroll
    for (int off = 1; off < 256; off <<= 1) {
        int a = 0;
        if (t < 256 && t >= off) a = stmp[t - off];
        __syncthreads();
        if (t < 256) stmp[t] += a;
        __syncthreads();
    }
    if (t < 256) ns[t] = stmp[t] - vcnt;
    __syncthreads();
    for (int i = t; i < ne; i += 512) {
        unsigned pk = eb[i];
        int pos = atomicAdd(&ns[pk >> 17], 1);
        stage[pos] = (int)(pk & 0x1FFFFu);
    }
    __syncthreads();

    // ---- agg: 4 lanes/node (lane tt owns h2 quad tt; head = tt>>1), 2 chunks ----
    int g = t >> 2, tt = t & 3, head = tt >> 1;
    const float4* h4 = reinterpret_cast<const float4*>(h2);
    const float2* als22 = reinterpret_cast<const float2*>(als2);
#pragma unroll
    for (int c = 0; c < 2; ++c) {
        int j = c * 128 + g;
        int n = node0 + j;
        bool act = j < nn;
        int e = act ? nh[j] : 0;
        int st = act ? (ns[j] - e) : 0;
        float aldv = act ? ald2L[j * 2 + head] : 0.f;
        float dA = 0.f, aA0 = 0.f, aA1 = 0.f, aA2 = 0.f, aA3 = 0.f;
        float dB = 0.f, aB0 = 0.f, aB1 = 0.f, aB2 = 0.f, aB3 = 0.f;
        int h = e >> 1;
        for (int i = 0; i < h; ++i) {
            int sA = stage[st + i];
            int sB = stage[st + h + i];
            float2 avA = als22[sA];
            float2 avB = als22[sB];
            float vA = lrelu((head ? avA.y : avA.x) + aldv);
            float vB = lrelu((head ? avB.y : avB.x) + aldv);
            float4 hA = h4[(size_t)sA * 4 + tt];
            float4 hB = h4[(size_t)sB * 4 + tt];
            float pA = __expf(vA);
            float pB = __expf(vB);
            dA += pA;                  dB += pB;
            aA0 = fmaf(pA, hA.x, aA0); aB0 = fmaf(pB, hB.x, aB0);
            aA1 = fmaf(pA, hA.y, aA1); aB1 = fmaf(pB, hB.y, aB1);
            aA2 = fmaf(pA, hA.z, aA2); aB2 = fmaf(pB, hB.z, aB2);
            aA3 = fmaf(pA, hA.w, aA3); aB3 = fmaf(pB, hB.w, aB3);
        }
        if (e & 1) {
            int s = stage[st + e - 1];
            float2 av = als22[s];
            float v = lrelu((head ? av.y : av.x) + aldv);
            float4 hs = h4[(size_t)s * 4 + tt];
            float p = __expf(v);
            dA += p;
            aA0 = fmaf(p, hs.x, aA0); aA1 = fmaf(p, hs.y, aA1);
            aA2 = fmaf(p, hs.z, aA2); aA3 = fmaf(p, hs.w, aA3);
        }
        // self loop + normalize + head
        float dot = 0.f;
        if (act) {
            float2 av = als22[n];
            float ps = __expf(lrelu((head ? av.y : av.x) + aldv));
            float4 hn = h4[(size_t)n * 4 + tt];
            float inv = 1.f / (dA + dB + ps + 1e-16f);
            float v0 = (aA0 + aB0 + ps * hn.x) * inv + sb2[tt * 4 + 0];
            float v1 = (aA1 + aB1 + ps * hn.y) * inv + sb2[tt * 4 + 1];
            float v2 = (aA2 + aB2 + ps * hn.z) * inv + sb2[tt * 4 + 2];
            float v3 = (aA3 + aB3 + ps * hn.w) * inv + sb2[tt * 4 + 3];
            v0 = v0 > 0.f ? v0 : expm1f(v0);
            v1 = v1 > 0.f ? v1 : expm1f(v1);
            v2 = v2 > 0.f ? v2 : expm1f(v2);
            v3 = v3 > 0.f ? v3 : expm1f(v3);
            dot = v0 * slw[tt * 4 + 0] + v1 * slw[tt * 4 + 1]
                + v2 * slw[tt * 4 + 2] + v3 * slw[tt * 4 + 3];
        }
        dot += __shfl_xor(dot, 1);
        dot += __shfl_xor(dot, 2);
        if (act && tt == 0) out[n] = 1.f / (1.f + __expf(-(dot + lb[0])));
    }
}

extern "C" void kernel_launch(void* const* d_in, const int* in_sizes, int n_in,
                              void* d_out, int out_size, void* d_ws, size_t ws_size,
                              hipStream_t stream) {
    const float* x     = (const float*)d_in[0];
    const int*   eidx  = (const int*)d_in[1];
    const float* W1    = (const float*)d_in[2];
    const float* as1   = (const float*)d_in[3];
    const float* ad1   = (const float*)d_in[4];
    const float* b1    = (const float*)d_in[5];
    const float* W2    = (const float*)d_in[6];
    const float* as2   = (const float*)d_in[7];
    const float* ad2   = (const float*)d_in[8];
    const float* b2    = (const float*)d_in[9];
    const float* lin_w = (const float*)d_in[10];
    const float* lin_b = (const float*)d_in[11];
    float* out = (float*)d_out;

    const int N = in_sizes[0] / 4;
    const int E = in_sizes[1] / 2;
    const int* src = eidx;
    const int* dst = eidx + E;
    const int NB = (N + BMASK) >> SHIFT;   // 391 buckets of 256 nodes

    // ---- workspace layout ----
    int*      bcur = (int*)d_ws;                         // 512
    unsigned* ebuf = (unsigned*)(bcur + 512);            // NB*CAPB
    float*    h2   = (float*)(ebuf + (size_t)NB * CAPB); // N*16
    float*    als2 = h2 + (size_t)N * 16;                // N*2
    float*    ald2 = als2 + (size_t)N * 2;               // N*2

    hipMemsetAsync(bcur, 0, 512 * sizeof(int), stream);
    kb_scatter<<<(E + 4095) / 4096, 256, 0, stream>>>(src, dst, bcur, ebuf, E);
    kbA1<<<NB, 512, 0, stream>>>(x, W1, as1, ad1, b1, W2, as2, ad2,
                                 bcur, ebuf, h2, als2, ald2, N);
    kbA2<<<NB, 512, 0, stream>>>(h2, als2, ald2, b2, lin_w, lin_b,
                                 bcur, ebuf, out, N);
}